// Round 7
// baseline (299.505 us; speedup 1.0000x reference)
//
#include <hip/hip_runtime.h>
#include <hip/hip_bf16.h>

#define NB 8
#define NTOK 16384           // tokens per batch (128*128)
#define TOTTOK (NB*NTOK)     // 131072

typedef __hip_bfloat16 bf16;
typedef __attribute__((ext_vector_type(8))) short bfrag;   // 8 bf16 = 4 VGPR
typedef __attribute__((ext_vector_type(4))) float ffrag;   // 4 fp32 acc

#define MFMA(a,b,c) __builtin_amdgcn_mfma_f32_16x16x32_bf16(a,b,c,0,0,0)

__device__ __forceinline__ float b2f(bf16 v){ return __bfloat162float(v); }
__device__ __forceinline__ bf16 f2b(float v){ return __float2bfloat16(v); }
__device__ __forceinline__ float bfu(unsigned short u){
    union { float f; unsigned v; } x; x.v = ((unsigned)u) << 16; return x.f; }
__device__ __forceinline__ unsigned short bu(bf16 b){
    union { bf16 b; unsigned short u; } x; x.b = b; return x.u; }
__device__ __forceinline__ void ld4(const bf16* p, float* f){
    uint2 r = *(const uint2*)p;
    f[0]=bfu(r.x & 0xffff); f[1]=bfu(r.x >> 16); f[2]=bfu(r.y & 0xffff); f[3]=bfu(r.y >> 16);
}
__device__ __forceinline__ float fastrcp(float x){
    float r; asm("v_rcp_f32 %0, %1" : "=v"(r) : "v"(x)); return r; }
// HW packed f32->bf16 convert (RNE), single instruction (no builtin on gfx950)
__device__ __forceinline__ unsigned cvtpk(float lo, float hi){
    unsigned r; asm("v_cvt_pk_bf16_f32 %0,%1,%2" : "=v"(r) : "v"(lo), "v"(hi)); return r; }
// scalar bf16 store via HW convert: 1 VALU + 1 ds_write_b16
__device__ __forceinline__ void stb(bf16* p, float v){
    unsigned r; asm("v_cvt_pk_bf16_f32 %0,%1,%1" : "=v"(r) : "v"(v));
    *(unsigned short*)p = (unsigned short)r; }
// tanh-form GELU, exp2-native: gelu = x - x/(z+1), z = 2^(x*(2.3022077 + 0.1029425 x^2))
__device__ __forceinline__ float gelu_t(float x){
    float x2 = x*x;
    float y  = x * fmaf(x2, 0.1029425f, 2.3022077f);
    float z  = exp2f(y);
    float rc = fastrcp(z + 1.f);
    return x - x*rc;
}
// A/B fragment: matrix row-major [rows][K]; lane L: row += L&15, k += (L>>4)*8.
// stride*2 bytes MUST be a multiple of 16 (b128 alignment).
__device__ __forceinline__ bfrag ld_frag(const bf16* p, int stride){
    int lane = threadIdx.x & 63;
    return *(const bfrag*)(p + (lane & 15)*stride + (lane >> 4)*8);
}

// ============ weight-image layout in workspace (bf16 elements) ============
#define WI_QKV   0        // [3][64][72]  (pad cols 64..71 = 0)         13824
#define WI_OW    13824    // [64][72]                                    4608
#define WI_CW    18432    // [64][72]                                    4608
#define WI_W1    23040    // [8 chunks][32][72]                         18432
#define WI_W2    41472    // [64][256] k-xor-swizzled W2T image         16384
#define WI_CONST 57856    // ln1w|ln1b|qb|kb|vb|ob|ln2w|ln2b|b1(256)|b2|cb  896
#define WI_TOT   58752

__global__ __launch_bounds__(256) void wprep_kernel(
    const float* __restrict__ qw, const float* __restrict__ kw, const float* __restrict__ vw,
    const float* __restrict__ ow, const float* __restrict__ cw,
    const float* __restrict__ w1, const float* __restrict__ w2,
    const float* __restrict__ ln1w, const float* __restrict__ ln1b,
    const float* __restrict__ qb, const float* __restrict__ kb_, const float* __restrict__ vb,
    const float* __restrict__ ob, const float* __restrict__ ln2w, const float* __restrict__ ln2b,
    const float* __restrict__ b1, const float* __restrict__ b2, const float* __restrict__ cb,
    bf16* __restrict__ WI)
{
    int gid = blockIdx.x*256 + threadIdx.x;
    if (gid >= WI_TOT) return;
    float v = 0.f;
    if (gid < WI_OW){                          // qkv: [o][ii] = w[ii*64+o]
        int m = gid / 4608, r = gid % 4608;
        int o = r / 72, ii = r % 72;
        const float* src = (m==0)? qw : (m==1)? kw : vw;
        if (ii < 64) v = src[ii*64 + o];
    } else if (gid < WI_CW){                   // ow: [o][ii] = ow[ii*64+o]
        int r = gid - WI_OW;
        int o = r / 72, ii = r % 72;
        if (ii < 64) v = ow[ii*64 + o];
    } else if (gid < WI_W1){                   // cw: [co][ii] = cw[co*64+ii]
        int r = gid - WI_CW;
        int co = r / 72, ii = r % 72;
        if (ii < 64) v = cw[co*64 + ii];
    } else if (gid < WI_W2){                   // w1 chunk gg: [ol][ii] = w1[ii*256+gg*32+ol]
        int r = gid - WI_W1;
        int gg = r / 2304, rr = r % 2304;
        int ol = rr / 72, ii = rr % 72;
        if (ii < 64) v = w1[ii*256 + gg*32 + ol];
    } else if (gid < WI_CONST){                // w2t swizzled image (inverse map)
        int a = gid - WI_W2;
        int o = a >> 8, ra = a & 255;
        int blk = ra >> 3, wi = ra & 7;
        int k = ((blk ^ (o & 7)) << 3) | wi;
        v = w2[k*64 + o];
    } else {                                   // consts
        int r = gid - WI_CONST;
        if      (r <  64) v = ln1w[r];
        else if (r < 128) v = ln1b[r-64];
        else if (r < 192) v = qb[r-128];
        else if (r < 256) v = kb_[r-192];
        else if (r < 320) v = vb[r-256];
        else if (r < 384) v = ob[r-320];
        else if (r < 448) v = ln2w[r-384];
        else if (r < 512) v = ln2b[r-448];
        else if (r < 768) v = b1[r-512];
        else if (r < 832) v = b2[r-768];
        else              v = cb[r-832];
    }
    WI[gid] = f2b(v);
}

// ============ FiLM pool: te [B,C,N] -> pool[b*1024 + c*16 + region] (sums over 32x32 regions) ============
__global__ __launch_bounds__(256) void pool_kernel(const float* __restrict__ te,
                                                   float* __restrict__ pool)
{
    int blk = blockIdx.x;            // b*64 + c
    const float* src = te + (size_t)blk * NTOK;
    int tid = threadIdx.x;
    __shared__ float R[16];
    if (tid < 16) R[tid] = 0.f;
    __syncthreads();
    int rw = (tid >> 3) & 3;         // w-region, constant per thread
    float acc[4] = {0.f, 0.f, 0.f, 0.f};
    #pragma unroll
    for (int u = 0; u < 16; ++u){
        float4 v = *(const float4*)(src + u*1024 + tid*4);
        acc[u >> 2] += v.x + v.y + v.z + v.w;   // rh = u>>2 (statically indexed)
    }
    #pragma unroll
    for (int rh = 0; rh < 4; ++rh) atomicAdd(&R[rh*4 + rw], acc[rh]);
    __syncthreads();
    if (tid < 16) pool[blk*16 + tid] = R[tid];
}

// ============ FiLM MLP: pool[B,1024] (unnormalized sums) -> gb[B,128] ============
__global__ __launch_bounds__(128) void film_kernel(const float* __restrict__ pool,
        const float* __restrict__ m1w, const float* __restrict__ m1b,
        const float* __restrict__ m2w, const float* __restrict__ m2b,
        float* __restrict__ gb){
    int b = blockIdx.x; int j = threadIdx.x;
    __shared__ float tel[1024];
    __shared__ float hm[128];
    for (int i = j; i < 1024; i += 128) tel[i] = pool[b*1024 + i] * (1.f/1024.f);
    __syncthreads();
    float s = m1b[j];
    for (int i = 0; i < 1024; ++i) s = fmaf(tel[i], m1w[i*128 + j], s);
    hm[j] = (s > 0.f) ? s : 0.01f*s;
    __syncthreads();
    float g = m2b[j];
    for (int i = 0; i < 128; ++i) g = fmaf(hm[i], m2w[i*128 + j], g);
    gb[b*128 + j] = g;
}

// ============ MEGA kernel: full TIAM block per 128-token chunk, 512 threads ============
// LDS map (manual overlays, 81920 B total -> 2 blocks/CU, 16 waves/CU):
//  [    0,16384) TE2 [128][64] te -> h (fused in o-proj epilogue)      -> OT [64][128]
//  [16384,34816) XTt [128][72] x tile -> K -> Pw(8x[16][64]) -> HN [128][72] (+W1X dbuf in gg loop) -> h2
//  [34816,53248) Tx temp [64][136] -> PN [128][72] LN1-out -> Q/O -> W1S+P -> CWs
//  [53248,80896) Tt temp [64][136] -> WT 3x[64][72] -> VT [80][136] -> OWT [64][72]
//  [47616,80384) W2T [64][256] k-xor-swizzled (staged during LN2; phase6)
//  [80896,81920) CON consts (restaged per phase)
#define OFF_TE2 0
#define OFF_XT  16384
#define OFF_PN  34816
#define OFF_WT  53248
#define OFF_W2T 47616
#define OFF_CON 80896
#define SCALE_Q 0.72134752044448170f   // 0.5 * log2(e): fold softmax scale + exp2 conv into Q

// LayerNorm over 64 channels, 4 threads/token, vectorized uint4 LDS I/O.
// Octet XOR o' = o ^ (tok&7): stride-128B source reads become perfectly bank-even.
__device__ __forceinline__ void ln_phase(const bf16* S, bf16* D,
                                         const bf16* Wt, const bf16* Bs, int tid)
{
    int tok = tid >> 2, q4 = tid & 3;
    float vals[16];
    int op2[2];
    float s = 0.f, s2 = 0.f;
    #pragma unroll
    for (int u8 = 0; u8 < 2; ++u8){
        int o = (q4*2 + u8) ^ (tok & 7);
        op2[u8] = o;
        uint4 v = *(const uint4*)(S + tok*64 + o*8);
        const unsigned* ap = &v.x;
        float* vp = vals + u8*8;
        #pragma unroll
        for (int e = 0; e < 4; ++e){
            float lo = bfu(ap[e] & 0xffff), hi = bfu(ap[e] >> 16);
            vp[e*2] = lo; vp[e*2+1] = hi;
            s += lo + hi;
            s2 = fmaf(lo, lo, fmaf(hi, hi, s2));
        }
    }
    s  += __shfl_xor(s, 1, 64);  s2 += __shfl_xor(s2, 1, 64);
    s  += __shfl_xor(s, 2, 64);  s2 += __shfl_xor(s2, 2, 64);
    float mean = s * (1.f/64.f);
    float var  = s2 * (1.f/64.f) - mean*mean;
    float rstd = rsqrtf(var + 1e-5f);
    #pragma unroll
    for (int u8 = 0; u8 < 2; ++u8){
        int cc0 = op2[u8]*8;
        uint4 wv = *(const uint4*)(Wt + cc0);
        uint4 bv = *(const uint4*)(Bs + cc0);
        const unsigned* wp = &wv.x;
        const unsigned* bp = &bv.x;
        uint4 o; unsigned* opp = &o.x;
        #pragma unroll
        for (int e = 0; e < 4; ++e){
            float lo = (vals[u8*8+e*2]  -mean)*rstd*bfu(wp[e] & 0xffff) + bfu(bp[e] & 0xffff);
            float hi = (vals[u8*8+e*2+1]-mean)*rstd*bfu(wp[e] >> 16)    + bfu(bp[e] >> 16);
            opp[e] = cvtpk(lo, hi);
        }
        *(uint4*)(D + tok*72 + cc0) = o;
    }
}

__global__ __launch_bounds__(512,4) void mega_kernel(
    const float* __restrict__ x, const float* __restrict__ te,
    const bf16* __restrict__ WI, const float* __restrict__ gb, float* __restrict__ out)
{
    __shared__ __align__(16) char sm[81920];
    bf16* TE2 = (bf16*)(sm + OFF_TE2);
    bf16* XT  = (bf16*)(sm + OFF_XT);
    bf16* PN  = (bf16*)(sm + OFF_PN);
    bf16* WT  = (bf16*)(sm + OFF_WT);
    bf16* VT  = (bf16*)(sm + OFF_WT);
    bf16* OWT = (bf16*)(sm + OFF_WT);
    bf16* W1S = (bf16*)(sm + OFF_PN);
    bf16* W1X = (bf16*)(sm + OFF_XT) + 4608;   // dbuf in dead XT region (rows 64..95)
    bf16* P   = (bf16*)(sm + OFF_PN + 4608);
    bf16* CWs = (bf16*)(sm + OFF_PN);
    bf16* W2T = (bf16*)(sm + OFF_W2T);
    bf16* CON = (bf16*)(sm + OFF_CON);
    bf16* OT  = (bf16*)(sm + OFF_TE2);

    int tid = threadIdx.x;
    int w = tid >> 6, lane = tid & 63;
    int g = lane >> 4, c = lane & 15;
    int t0g = blockIdx.x * 128;               // global token base
    int b = t0g >> 14, n0 = t0g & (NTOK-1);
    const ffrag fz = {0.f,0.f,0.f,0.f};

    // ---------- phase 0: direct fp32 load + in-LDS transpose (x -> XT, te -> TE2) ----------
    {
        bf16* Tx = PN;    // temp [64][136] channel-major (PN region, dead now)
        bf16* Tt = WT;    // temp [64][136] channel-major (WT region, staged later)
        if (tid < 16) ((uint4*)CON)[tid] = ((const uint4*)(WI + WI_CONST))[tid];  // ln1w|ln1b
        int c0 = tid >> 3, j16 = (tid & 7) * 16;
        const float* xp = x  + (size_t)b*64*NTOK + (size_t)c0*NTOK + n0 + j16;
        const float* tp = te + (size_t)b*64*NTOK + (size_t)c0*NTOK + n0 + j16;
        float4 a0 = *(const float4*)(xp);
        float4 a1 = *(const float4*)(xp + 4);
        float4 a2 = *(const float4*)(xp + 8);
        float4 a3 = *(const float4*)(xp + 12);
        float4 e0 = *(const float4*)(tp);
        float4 e1 = *(const float4*)(tp + 4);
        float4 e2 = *(const float4*)(tp + 8);
        float4 e3 = *(const float4*)(tp + 12);
        uint4 o0, o1;
        o0.x = cvtpk(a0.x, a0.y); o0.y = cvtpk(a0.z, a0.w);
        o0.z = cvtpk(a1.x, a1.y); o0.w = cvtpk(a1.z, a1.w);
        o1.x = cvtpk(a2.x, a2.y); o1.y = cvtpk(a2.z, a2.w);
        o1.z = cvtpk(a3.x, a3.y); o1.w = cvtpk(a3.z, a3.w);
        *(uint4*)(Tx + c0*136 + j16)     = o0;
        *(uint4*)(Tx + c0*136 + j16 + 8) = o1;
        o0.x = cvtpk(e0.x, e0.y); o0.y = cvtpk(e0.z, e0.w);
        o0.z = cvtpk(e1.x, e1.y); o0.w = cvtpk(e1.z, e1.w);
        o1.x = cvtpk(e2.x, e2.y); o1.y = cvtpk(e2.z, e2.w);
        o1.z = cvtpk(e3.x, e3.y); o1.w = cvtpk(e3.z, e3.w);
        *(uint4*)(Tt + c0*136 + j16)     = o0;
        *(uint4*)(Tt + c0*136 + j16 + 8) = o1;
        __syncthreads();
        #pragma unroll
        for (int p = 0; p < 2; ++p){
            int idx = p*512 + tid;
            int tok = idx & 127, seg = idx >> 7;      // seg constant per wave -> 2-way banks
            const bf16* rx = Tx + seg*1088 + tok;
            const bf16* rt = Tt + seg*1088 + tok;
            uint4 ox, ot;
            ox.x = (unsigned)bu(rx[0])   | ((unsigned)bu(rx[136]) << 16);
            ox.y = (unsigned)bu(rx[272]) | ((unsigned)bu(rx[408]) << 16);
            ox.z = (unsigned)bu(rx[544]) | ((unsigned)bu(rx[680]) << 16);
            ox.w = (unsigned)bu(rx[816]) | ((unsigned)bu(rx[952]) << 16);
            *(uint4*)(XT + tok*72 + seg*8) = ox;
            ot.x = (unsigned)bu(rt[0])   | ((unsigned)bu(rt[136]) << 16);
            ot.y = (unsigned)bu(rt[272]) | ((unsigned)bu(rt[408]) << 16);
            ot.z = (unsigned)bu(rt[544]) | ((unsigned)bu(rt[680]) << 16);
            ot.w = (unsigned)bu(rt[952-136]) | ((unsigned)bu(rt[952]) << 16);
            *(uint4*)(TE2 + tok*64 + seg*8) = ot;
        }
    }
    __syncthreads();
    // ---------- phase 1: LN1 (TE2 -> PN, over dead Tx) + stage qkv weights (over dead Tt) ----------
    {
        ln_phase(TE2, PN, CON, CON + 64, tid);
        const uint4* wq = (const uint4*)(WI + WI_QKV);   // 1728 uint4 = 3x[64][72]
        for (int i = tid; i < 1728; i += 512) ((uint4*)WT)[i] = wq[i];
    }
    __syncthreads();
    // ---------- phase 2: QKV MFMA (8 waves x 16-row strips) ----------
    {
        if (tid < 24) ((uint4*)CON)[tid] = ((const uint4*)(WI + WI_CONST + 128))[tid]; // qb|kb|vb
        ffrag accQ[4], accK[4], accV[4];
        #pragma unroll
        for (int nt=0;nt<4;++nt){ accQ[nt]=fz; accK[nt]=fz; accV[nt]=fz; }
        bfrag aQ[2], aX[2];
        #pragma unroll
        for (int k2=0;k2<2;++k2){
            aQ[k2] = ld_frag(PN + (w*16)*72 + k2*32, 72);
            aX[k2] = ld_frag(XT + (w*16)*72 + k2*32, 72);
        }
        __builtin_amdgcn_s_setprio(1);
        for (int nt = 0; nt < 4; ++nt){
            #pragma unroll
            for (int k2 = 0; k2 < 2; ++k2){
                bfrag bq2 = ld_frag(WT +        nt*16*72 + k2*32, 72);
                bfrag bk2 = ld_frag(WT + 4608 + nt*16*72 + k2*32, 72);
                bfrag bv2 = ld_frag(WT + 9216 + nt*16*72 + k2*32, 72);
                accQ[nt] = MFMA(aQ[k2], bq2, accQ[nt]);
                accK[nt] = MFMA(aX[k2], bk2, accK[nt]);
                accV[nt] = MFMA(aX[k2], bv2, accV[nt]);
            }
        }
        __builtin_amdgcn_s_setprio(0);
        __syncthreads();   // all PN/XT/WT reads done; regions become Q / K / VT
        int rq = g*4;
        #pragma unroll
        for (int nt=0;nt<4;++nt){
            int n = nt*16 + c;
            float bq3 = b2f(CON[n]), bk3 = b2f(CON[64+n]), bv3 = b2f(CON[128+n]);
            #pragma unroll
            for (int r=0;r<4;++r){
                int m = w*16 + rq + r;
                // Q/K pair-write: lanes c,c+1 exchange; even lane writes Q b32, odd writes K b32
                float qv = (accQ[nt][r] + bq3) * SCALE_Q;
                float kv = accK[nt][r] + bk3;
                float qp = __shfl_xor(qv, 1, 64);
                float kp = __shfl_xor(kv, 1, 64);
                if (!(c & 1)) *(unsigned*)(PN + m*72 + n)     = cvtpk(qv, qp);
                else          *(unsigned*)(XT + m*72 + n - 1) = cvtpk(kp, kv);
                // V -> VT transposed (scatter, stays scalar), half-tile key perm:
                int vcol = ((m >> 6) << 6) + (m & 15)*4 + ((m >> 4) & 3);
                stb(VT + (5*(n>>2) + (n&3))*136 + vcol, accV[nt][r] + bv3);
            }
        }
        // ones rows (row 5h+4) for the l-trick — one uint4 per thread
        if (tid < 256){
            int row = 5*(tid >> 4) + 4, col8 = (tid & 15)*8;
            uint4 ov; ov.x = ov.y = ov.z = ov.w = 0x3f803f80u;
            *(uint4*)(VT + row*136 + col8) = ov;
        }
    }
    __syncthreads();
    // ---------- phase 3: attention (block-diag, 16 heads, hd=4; 2 heads/wave, K-halved) ----------
    {
        bfrag bq[8];
        #pragma unroll
        for (int nt = 0; nt < 8; ++nt) bq[nt] = ld_frag(XT + nt*16*72 + (w>>2)*32, 72);
        __syncthreads();                       // K region becomes P scratch
        bf16* Pw = XT + w*1024;                // per-wave [16][64]
        #pragma unroll 1
        for (int hh = 0; hh < 2; ++hh){
            int h = w*2 + hh;
            int ag = w & 3;                    // active quad for A build
            bfrag bv4[4];                      // [kh*2 + ks]
            #pragma unroll
            for (int kk = 0; kk < 4; ++kk)
                bv4[kk] = ld_frag(VT + (5*h)*136 + (kk>>1)*64 + (kk&1)*32, 136);
            #pragma unroll 2
            for (int qt = 0; qt < 8; ++qt){
                int q = qt*16 + c;
                uint2 qv = *(const uint2*)(PN + q*72 + h*4);
                union { bfrag f; uint2 u[2]; } A;
                uint2 z2; z2.x = 0u; z2.y = 0u;
                uint2 sel = (g == ag) ? qv : z2;
                if (hh){ A.u[0] = z2;  A.u[1] = sel; }
                else   { A.u[0] = sel; A.u[1] = z2;  }
                ffrag og = fz;
                #pragma unroll
                for (int kh = 0; kh < 2; ++kh){
                    ffrag acc[4];
                    __builtin_amdgcn_s_setprio(1);
                    #pragma unroll
                    for (int nt = 0; nt < 4; ++nt) acc[nt] = MFMA(A.f, bq[kh*4+nt], fz);
                    __builtin_amdgcn_s_setprio(0);
                    #pragma unroll
                    for (int nt = 0; nt < 4; ++nt){
                        #pragma unroll
                        for (int r = 0; r < 4; ++r) acc[nt][r] = exp2f(acc[nt][r]);
                    }
                    // pack half-tile P [16][64]: row 4g+r, logical octet c>>1 (XOR row&7),
                    // within-octet (c&1)*4 + nt  (key perm kp'' = (m&15)*4 + (m>>4))
                    #pragma unroll
                    for (int r = 0; r < 4; ++r){
                        uint2 pk;
                        pk.x = cvtpk(acc[0][r], acc[1][r]);
                        pk.y = cvtpk(acc[2][r], acc[3][r]);
                        int row = 4*g + r;
                        *(uint2*)(Pw + row*64 + (((c>>1) ^ (row&7)) << 3) + ((c&1) << 2)) = pk;
                    }
                    // PV partial over this K-half (ones col 4 accumulates l)
                    __builtin_amdgcn_s_setprio(1);
                    #pragma unroll
                    for (int ks = 0; ks < 2; ++ks){
                        bfrag ap = *(const bfrag*)(Pw + c*64 + (((ks*4 + g) ^ (c&7)) << 3));
                        og = MFMA(ap, bv4[kh*2 + ks], og);
                    }
                    __builtin_amdgcn_s_setprio(0);
                }
                // broadcast l from lanes c==4, normalize; pair-write O (c=0,2 write b32)
                #pragma unroll
                for (int r = 0; r < 4; ++r){
                    float lr = __shfl(og[r], (lane & 48) | 4, 64);
                    float o  = og[r] * fastrcp(lr);
                    float op = __shfl_xor(o, 1, 64);
                    if (c < 4 && !(c & 1))
                        *(unsigned*)(PN + (qt*16 + 4*g + r)*72 + h*4 + c) = cvtpk(o, op);
                }
            }
        }
    }
    __syncthreads();
    // ---------- phase 3.5: o-proj (O @ ow^T + ob) + residual te, fused -> h in TE2 ----------
    {
        const uint4* oi = (const uint4*)(WI + WI_OW);
        for (int i = tid; i < 576; i += 512) ((uint4*)OWT)[i] = oi[i];
        if (tid < 24) ((uint4*)CON)[tid] = ((const uint4*)(WI + WI_CONST + 320))[tid]; // ob|ln2w|ln2b
        __syncthreads();
        ffrag acc2[4];
        #pragma unroll
        for (int nt=0;nt<4;++nt) acc2[nt] = fz;
        bfrag af2[2];
        #pragma unroll
        for (int k2=0;k2<2;++k2)
            af2[k2] = ld_frag(PN + (w*16)*72 + k2*32, 72);
        __builtin_amdgcn_s_setprio(1);
        #pragma unroll
        for (int nt=0;nt<4;++nt){
            #pragma unroll
            for (int k2=0;k2<2;++k2){
                bfrag bf_ = ld_frag(OWT + nt*16*72 + k2*32, 72);
                acc2[nt] = MFMA(af2[k2], bf_, acc2[nt]);
            }
        }
        __builtin_amdgcn_s_setprio(0);
        // epilogue: h = o-proj + ob + te, pair-write over te (even lane owns n,n+1)
        int rq = g*4;
        #pragma unroll
        for (int nt=0;nt<4;++nt){
            int n = nt*16 + c;
            float bo = b2f(CON[n]);
            #pragma unroll
            for (int r=0;r<4;++r){
                int m = w*16 + rq + r;
                float v  = acc2[nt][r] + bo;
                float vp = __shfl_xor(v, 1, 64);
                if (!(c & 1)){
                    unsigned t = *(unsigned*)(TE2 + m*64 + n);
                    *(unsigned*)(TE2 + m*64 + n) =
                        cvtpk(v + bfu(t & 0xffff), vp + bfu(t >> 16));
                }
            }
        }
    }
    __syncthreads();
    // ---------- phase 5: LN2 (TE2 -> HN in XT) with W2T staging split around it ----------
    {
        const uint4* w2i = (const uint4*)(WI + WI_W2);
        uint4 w2r0 = w2i[tid];               // issue early: HBM latency hides under LN2
        uint4 w2r1 = w2i[512 + tid];
        uint4 w2r2 = w2i[1024 + tid];
        uint4 w2r3 = w2i[1536 + tid];
        ln_phase(TE2, XT, CON + 64, CON + 128, tid);
        ((uint4*)W2T)[tid]        = w2r0;    // write late (W2T region dead since 3.5)
        ((uint4*)W2T)[512 + tid]  = w2r1;
        ((uint4*)W2T)[1024 + tid] = w2r2;
        ((uint4*)W2T)[1536 + tid] = w2r3;
    }
    __syncthreads();
    // ---------- phase 6: FFN (fc1+GELU+fc2, K-grouped, dbuf W1) + residual ----------
    {
        if (tid < 48) ((uint4*)CON)[tid] = ((const uint4*)(WI + WI_CONST + 512))[tid]; // b1|b2|cb
        bfrag af[2];
        #pragma unroll
        for (int k2=0;k2<2;++k2)
            af[k2] = ld_frag(XT + (w*16)*72 + k2*32, 72);
        ffrag acc2[4];
        #pragma unroll
        for (int nt=0;nt<4;++nt) acc2[nt] = fz;
        int rq = g*4;
        // register prefetch of W1 chunks (288 uint4 each); double-buffered LDS (W1S / W1X)
        const uint4* w1i = (const uint4*)(WI + WI_W1);
        uint4 pA;
        if (tid < 288) pA = w1i[tid];
        for (int gg = 0; gg < 8; ++gg){
            bf16* Wb = (gg & 1) ? W1X : W1S;
            if (tid < 288){
                ((uint4*)Wb)[tid] = pA;
                if (gg < 7) pA = w1i[(gg+1)*288 + tid];
            }
            __syncthreads();       // single barrier per iteration (dbuf makes 2nd unnecessary)
            ffrag accg[2];
            #pragma unroll
            for (int ntl=0;ntl<2;++ntl) accg[ntl] = fz;
            __builtin_amdgcn_s_setprio(1);
            #pragma unroll
            for (int ntl=0;ntl<2;++ntl){
                #pragma unroll
                for (int k2=0;k2<2;++k2){
                    bfrag bf_ = ld_frag(Wb + ntl*16*72 + k2*32, 72);
                    accg[ntl] = MFMA(af[k2], bf_, accg[ntl]);
                }
            }
            __builtin_amdgcn_s_setprio(0);
            // GELU -> P pair-write (even lane writes n,n+1; same octet since n even)
            // octet XOR-swizzle (octet ^= (row>>1)&3) -> fc2 A-frag reads bank-even
            #pragma unroll
            for (int ntl=0;ntl<2;++ntl){
                int n = ntl*16 + c;
                float bb = b2f(CON[gg*32 + n]);
                #pragma unroll
                for (int r=0;r<4;++r){
                    int m = w*16 + rq + r;
                    float gv = gelu_t(accg[ntl][r] + bb);
                    float gp = __shfl_xor(gv, 1, 64);
                    if (!(c & 1))
                        *(unsigned*)(P + m*32 + ((((n>>3) ^ ((m>>1)&3)) << 3) | (n & 7))) =
                            cvtpk(gv, gp);
                }
            }
            // fc2 partial (K-chunk gg), swizzled P + swizzled W2T frags
            {
                int rr = w*16 + c;
                bfrag ap = *(const bfrag*)(P + rr*32 + ((g ^ ((rr>>1)&3)) << 3));
                __builtin_amdgcn_s_setprio(1);
                #pragma unroll
                for (int nt=0;nt<4;++nt){
                    int n = nt*16 + c;
                    int chunk = gg*4 + g;
                    bfrag bf2 = *(const bfrag*)(W2T + n*256 + ((chunk ^ (n&7)) << 3));
                    acc2[nt] = MFMA(ap, bf2, acc2[nt]);
                }
                __builtin_amdgcn_s_setprio(0);
            }
        }
        // prefetch conv weights to regs (write after barrier; CWs region dead post-B9)
        const uint4* ci = (const uint4*)(WI + WI_CW);
        uint4 cw0 = ci[tid];
        uint4 cw1 = cw0;
        if (tid < 64) cw1 = ci[512 + tid];
        __syncthreads();   // B9: all Wb/P/W2T reads done; XT & CWs regions free
        // h2 = fc2 + b2 + h  -> h2 in XT, pair-write (even lane reads TE2 pair)
        #pragma unroll
        for (int nt=0;nt<4;++nt){
            int n = nt*16 + c;
            float bb = b2f(CON[256+n]);
            #pragma unroll
            for (int r=0;r<4;++r){
                int m = w*16 + rq + r;
                float v  = acc2[nt][r] + bb;
                float vp = __shfl_xor(v, 1, 64);
                if (!(c & 1)){
                    unsigned t = *(unsigned*)(TE2 + m*64 + n);
                    *(unsigned*)(XT + m*72 + n) =
                        cvtpk(v + bfu(t & 0xffff), vp + bfu(t >> 16));
                }
            }
        }
        // conv-weight staging from regs (same barrier window as h2 writes)
        ((uint4*)CWs)[tid] = cw0;
        if (tid < 64) ((uint4*)CWs)[512 + tid] = cw1;
    }
    __syncthreads();
    // ---------- phase 7: 1x1 conv -> OT [64][128] (over h-in-TE2 region; reads XT) ----------
    {
        bfrag ac[2];
        #pragma unroll
        for (int k2=0;k2<2;++k2) ac[k2] = ld_frag(CWs + ((w&3)*16)*72 + k2*32, 72);
        int rq = g*4;
        #pragma unroll
        for (int nt4 = 0; nt4 < 4; ++nt4){
            int nt = (w>>2)*4 + nt4;
            ffrag accc = fz;
            __builtin_amdgcn_s_setprio(1);
            #pragma unroll
            for (int k2=0;k2<2;++k2){
                bfrag bh = ld_frag(XT + nt*16*72 + k2*32, 72);
                accc = MFMA(ac[k2], bh, accc);
            }
            __builtin_amdgcn_s_setprio(0);
            int tok = nt*16 + c;
            #pragma unroll
            for (int r=0;r<4;++r){
                int co = (w&3)*16 + rq + r;
                stb(OT + co*128 + tok, accc[r] + b2f(CON[320+co]));
            }
        }
    }
    __syncthreads();
    // ---------- phase 8: out = (1+gamma)*(conv + x) + beta ----------
    {
        int cc = tid >> 3, seg = (tid & 7)*16;
        float gamma = 1.f + gb[b*128 + cc];
        float beta  = gb[b*128 + 64 + cc];
        const size_t gbase = (size_t)b*64*NTOK + (size_t)cc*NTOK + n0 + seg;
        #pragma unroll
        for (int u = 0; u < 4; ++u){
            float cv[4];
            ld4(OT + cc*128 + seg + u*4, cv);
            float4 xv = *(const float4*)(x + gbase + u*4);
            float4 ov;
            ov.x = fmaf(gamma, cv[0]+xv.x, beta);
            ov.y = fmaf(gamma, cv[1]+xv.y, beta);
            ov.z = fmaf(gamma, cv[2]+xv.z, beta);
            ov.w = fmaf(gamma, cv[3]+xv.w, beta);
            *(float4*)(out + gbase + u*4) = ov;
        }
    }
}

extern "C" void kernel_launch(void* const* d_in, const int* in_sizes, int n_in,
                              void* d_out, int out_size, void* d_ws, size_t ws_size,
                              hipStream_t stream){
    const float* x   = (const float*)d_in[0];
    const float* te  = (const float*)d_in[1];
    const float* qw  = (const float*)d_in[2];
    const float* qb  = (const float*)d_in[3];
    const float* kw  = (const float*)d_in[4];
    const float* kb  = (const float*)d_in[5];
    const float* vw  = (const float*)d_in[6];
    const float* vb  = (const float*)d_in[7];
    const float* ow  = (const float*)d_in[8];
    const float* ob  = (const float*)d_in[9];
    const float* ln1w= (const float*)d_in[10];
    const float* ln1b= (const float*)d_in[11];
    const float* ln2w= (const float*)d_in[12];
    const float* ln2b= (const float*)d_in[13];
    const float* w1  = (const float*)d_in[14];
    const float* b1  = (const float*)d_in[15];
    const float* w2  = (const float*)d_in[16];
    const float* b2  = (const float*)d_in[17];
    const float* cw  = (const float*)d_in[18];
    const float* cb  = (const float*)d_in[19];
    const float* m1w = (const float*)d_in[20];
    const float* m1b = (const float*)d_in[21];
    const float* m2w = (const float*)d_in[22];
    const float* m2b = (const float*)d_in[23];

    char* ws = (char*)d_ws;
    float* pool = (float*)(ws);                   // 32768 B
    float* gbp  = (float*)(ws + 32768);           // 4096 B
    bf16* WI    = (bf16*)(ws + 36864);            // 117504 B weight/const images

    wprep_kernel<<<(WI_TOT + 255)/256, 256, 0, stream>>>(
        qw, kw, vw, ow, cw, w1, w2,
        ln1w, ln1b, qb, kb, vb, ob, ln2w, ln2b, b1, b2, cb, WI);
    pool_kernel<<<NB*64, 256, 0, stream>>>(te, pool);
    film_kernel<<<NB, 128, 0, stream>>>(pool, m1w, m1b, m2w, m2b, gbp);
    mega_kernel<<<TOTTOK/128, 512, 0, stream>>>(x, te, WI, gbp, (float*)d_out);
}

// Round 8
// 284.758 us; speedup vs baseline: 1.0518x; 1.0518x over previous
//
#include <hip/hip_runtime.h>
#include <hip/hip_bf16.h>

#define NB 8
#define NTOK 16384           // tokens per batch (128*128)
#define TOTTOK (NB*NTOK)     // 131072

typedef __hip_bfloat16 bf16;
typedef __attribute__((ext_vector_type(8))) short bfrag;   // 8 bf16 = 4 VGPR
typedef __attribute__((ext_vector_type(4))) float ffrag;   // 4 fp32 acc

#define MFMA(a,b,c) __builtin_amdgcn_mfma_f32_16x16x32_bf16(a,b,c,0,0,0)

__device__ __forceinline__ float b2f(bf16 v){ return __bfloat162float(v); }
__device__ __forceinline__ bf16 f2b(float v){ return __float2bfloat16(v); }
__device__ __forceinline__ float bfu(unsigned short u){
    union { float f; unsigned v; } x; x.v = ((unsigned)u) << 16; return x.f; }
__device__ __forceinline__ unsigned short bu(bf16 b){
    union { bf16 b; unsigned short u; } x; x.b = b; return x.u; }
__device__ __forceinline__ void ld4(const bf16* p, float* f){
    uint2 r = *(const uint2*)p;
    f[0]=bfu(r.x & 0xffff); f[1]=bfu(r.x >> 16); f[2]=bfu(r.y & 0xffff); f[3]=bfu(r.y >> 16);
}
__device__ __forceinline__ float fastrcp(float x){
    float r; asm("v_rcp_f32 %0, %1" : "=v"(r) : "v"(x)); return r; }
// HW packed f32->bf16 convert (RNE), single instruction (no builtin on gfx950)
__device__ __forceinline__ unsigned cvtpk(float lo, float hi){
    unsigned r; asm("v_cvt_pk_bf16_f32 %0,%1,%2" : "=v"(r) : "v"(lo), "v"(hi)); return r; }
// scalar bf16 store via HW convert: 1 VALU + 1 ds_write_b16
__device__ __forceinline__ void stb(bf16* p, float v){
    unsigned r; asm("v_cvt_pk_bf16_f32 %0,%1,%1" : "=v"(r) : "v"(v));
    *(unsigned short*)p = (unsigned short)r; }
// tanh-form GELU, exp2-native: gelu = x - x/(z+1), z = 2^(x*(2.3022077 + 0.1029425 x^2))
__device__ __forceinline__ float gelu_t(float x){
    float x2 = x*x;
    float y  = x * fmaf(x2, 0.1029425f, 2.3022077f);
    float z  = exp2f(y);
    float rc = fastrcp(z + 1.f);
    return x - x*rc;
}
// A/B fragment: matrix row-major [rows][K]; lane L: row += L&15, k += (L>>4)*8.
// stride*2 bytes MUST be a multiple of 16 (b128 alignment).
__device__ __forceinline__ bfrag ld_frag(const bf16* p, int stride){
    int lane = threadIdx.x & 63;
    return *(const bfrag*)(p + (lane & 15)*stride + (lane >> 4)*8);
}

// ============ weight-image layout in workspace (bf16 elements) ============
#define WI_QKV   0        // [3][64][72]  (pad cols 64..71 = 0)         13824
#define WI_OW    13824    // [64][72]                                    4608
#define WI_CW    18432    // [64][72]                                    4608
#define WI_W1    23040    // [8 chunks][32][72]                         18432
#define WI_W2    41472    // [64][256] k-xor-swizzled W2T image         16384
#define WI_CONST 57856    // ln1w|ln1b|qb|kb|vb|ob|ln2w|ln2b|b1(256)|b2|cb  896
#define WI_TOT   58752

__global__ __launch_bounds__(256) void wprep_kernel(
    const float* __restrict__ qw, const float* __restrict__ kw, const float* __restrict__ vw,
    const float* __restrict__ ow, const float* __restrict__ cw,
    const float* __restrict__ w1, const float* __restrict__ w2,
    const float* __restrict__ ln1w, const float* __restrict__ ln1b,
    const float* __restrict__ qb, const float* __restrict__ kb_, const float* __restrict__ vb,
    const float* __restrict__ ob, const float* __restrict__ ln2w, const float* __restrict__ ln2b,
    const float* __restrict__ b1, const float* __restrict__ b2, const float* __restrict__ cb,
    bf16* __restrict__ WI)
{
    int gid = blockIdx.x*256 + threadIdx.x;
    if (gid >= WI_TOT) return;
    float v = 0.f;
    if (gid < WI_OW){                          // qkv: [o][ii] = w[ii*64+o]
        int m = gid / 4608, r = gid % 4608;
        int o = r / 72, ii = r % 72;
        const float* src = (m==0)? qw : (m==1)? kw : vw;
        if (ii < 64) v = src[ii*64 + o];
    } else if (gid < WI_CW){                   // ow: [o][ii] = ow[ii*64+o]
        int r = gid - WI_OW;
        int o = r / 72, ii = r % 72;
        if (ii < 64) v = ow[ii*64 + o];
    } else if (gid < WI_W1){                   // cw: [co][ii] = cw[co*64+ii]
        int r = gid - WI_CW;
        int co = r / 72, ii = r % 72;
        if (ii < 64) v = cw[co*64 + ii];
    } else if (gid < WI_W2){                   // w1 chunk gg: [ol][ii] = w1[ii*256+gg*32+ol]
        int r = gid - WI_W1;
        int gg = r / 2304, rr = r % 2304;
        int ol = rr / 72, ii = rr % 72;
        if (ii < 64) v = w1[ii*256 + gg*32 + ol];
    } else if (gid < WI_CONST){                // w2t swizzled image (inverse map)
        int a = gid - WI_W2;
        int o = a >> 8, ra = a & 255;
        int blk = ra >> 3, wi = ra & 7;
        int k = ((blk ^ (o & 7)) << 3) | wi;
        v = w2[k*64 + o];
    } else {                                   // consts
        int r = gid - WI_CONST;
        if      (r <  64) v = ln1w[r];
        else if (r < 128) v = ln1b[r-64];
        else if (r < 192) v = qb[r-128];
        else if (r < 256) v = kb_[r-192];
        else if (r < 320) v = vb[r-256];
        else if (r < 384) v = ob[r-320];
        else if (r < 448) v = ln2w[r-384];
        else if (r < 512) v = ln2b[r-448];
        else if (r < 768) v = b1[r-512];
        else if (r < 832) v = b2[r-768];
        else              v = cb[r-832];
    }
    WI[gid] = f2b(v);
}

// ============ FiLM pool: te [B,C,N] -> pool[b*1024 + c*16 + region] (sums over 32x32 regions) ============
__global__ __launch_bounds__(256) void pool_kernel(const float* __restrict__ te,
                                                   float* __restrict__ pool)
{
    int blk = blockIdx.x;            // b*64 + c
    const float* src = te + (size_t)blk * NTOK;
    int tid = threadIdx.x;
    __shared__ float R[16];
    if (tid < 16) R[tid] = 0.f;
    __syncthreads();
    int rw = (tid >> 3) & 3;         // w-region, constant per thread
    float acc[4] = {0.f, 0.f, 0.f, 0.f};
    #pragma unroll
    for (int u = 0; u < 16; ++u){
        float4 v = *(const float4*)(src + u*1024 + tid*4);
        acc[u >> 2] += v.x + v.y + v.z + v.w;   // rh = u>>2 (statically indexed)
    }
    #pragma unroll
    for (int rh = 0; rh < 4; ++rh) atomicAdd(&R[rh*4 + rw], acc[rh]);
    __syncthreads();
    if (tid < 16) pool[blk*16 + tid] = R[tid];
}

// ============ FiLM MLP: pool[B,1024] (unnormalized sums) -> gb[B,128] ============
__global__ __launch_bounds__(128) void film_kernel(const float* __restrict__ pool,
        const float* __restrict__ m1w, const float* __restrict__ m1b,
        const float* __restrict__ m2w, const float* __restrict__ m2b,
        float* __restrict__ gb){
    int b = blockIdx.x; int j = threadIdx.x;
    __shared__ float tel[1024];
    __shared__ float hm[128];
    for (int i = j; i < 1024; i += 128) tel[i] = pool[b*1024 + i] * (1.f/1024.f);
    __syncthreads();
    float s = m1b[j];
    for (int i = 0; i < 1024; ++i) s = fmaf(tel[i], m1w[i*128 + j], s);
    hm[j] = (s > 0.f) ? s : 0.01f*s;
    __syncthreads();
    float g = m2b[j];
    for (int i = 0; i < 128; ++i) g = fmaf(hm[i], m2w[i*128 + j], g);
    gb[b*128 + j] = g;
}

// ============ MEGA kernel: full TIAM block per 128-token chunk, 512 threads ============
// LDS map (manual overlays, 81920 B total -> 2 blocks/CU, 16 waves/CU):
//  [    0,16384) TE2 [128][64] te -> h (fused in o-proj epilogue)      -> OT [64][128]
//  [16384,34816) XTt [128][72] x tile -> K -> Pw(8x[16][64]) -> HN [128][72] (+W1X dbuf in gg loop) -> h2
//  [34816,53248) Tx temp [64][136] -> PN [128][72] LN1-out -> Q/O -> W1S+P -> CWs
//  [53248,80896) Tt temp [64][136] -> WT 3x[64][72] -> VT [80][136] -> OWT [64][72]
//  [47616,80384) W2T [64][256] k-xor-swizzled (staged during LN2; phase6)
//  [80896,81920) CON consts (restaged per phase)
#define OFF_TE2 0
#define OFF_XT  16384
#define OFF_PN  34816
#define OFF_WT  53248
#define OFF_W2T 47616
#define OFF_CON 80896
#define SCALE_Q 0.72134752044448170f   // 0.5 * log2(e): fold softmax scale + exp2 conv into Q

// LayerNorm over 64 channels, 4 threads/token, vectorized uint4 LDS I/O.
// Octet XOR o' = o ^ (tok&7): stride-128B source reads become perfectly bank-even.
__device__ __forceinline__ void ln_phase(const bf16* S, bf16* D,
                                         const bf16* Wt, const bf16* Bs, int tid)
{
    int tok = tid >> 2, q4 = tid & 3;
    float vals[16];
    int op2[2];
    float s = 0.f, s2 = 0.f;
    #pragma unroll
    for (int u8 = 0; u8 < 2; ++u8){
        int o = (q4*2 + u8) ^ (tok & 7);
        op2[u8] = o;
        uint4 v = *(const uint4*)(S + tok*64 + o*8);
        const unsigned* ap = &v.x;
        float* vp = vals + u8*8;
        #pragma unroll
        for (int e = 0; e < 4; ++e){
            float lo = bfu(ap[e] & 0xffff), hi = bfu(ap[e] >> 16);
            vp[e*2] = lo; vp[e*2+1] = hi;
            s += lo + hi;
            s2 = fmaf(lo, lo, fmaf(hi, hi, s2));
        }
    }
    s  += __shfl_xor(s, 1, 64);  s2 += __shfl_xor(s2, 1, 64);
    s  += __shfl_xor(s, 2, 64);  s2 += __shfl_xor(s2, 2, 64);
    float mean = s * (1.f/64.f);
    float var  = s2 * (1.f/64.f) - mean*mean;
    float rstd = rsqrtf(var + 1e-5f);
    #pragma unroll
    for (int u8 = 0; u8 < 2; ++u8){
        int cc0 = op2[u8]*8;
        uint4 wv = *(const uint4*)(Wt + cc0);
        uint4 bv = *(const uint4*)(Bs + cc0);
        const unsigned* wp = &wv.x;
        const unsigned* bp = &bv.x;
        uint4 o; unsigned* opp = &o.x;
        #pragma unroll
        for (int e = 0; e < 4; ++e){
            float lo = (vals[u8*8+e*2]  -mean)*rstd*bfu(wp[e] & 0xffff) + bfu(bp[e] & 0xffff);
            float hi = (vals[u8*8+e*2+1]-mean)*rstd*bfu(wp[e] >> 16)    + bfu(bp[e] >> 16);
            opp[e] = cvtpk(lo, hi);
        }
        *(uint4*)(D + tok*72 + cc0) = o;
    }
}

__global__ __launch_bounds__(512,4) void mega_kernel(
    const float* __restrict__ x, const float* __restrict__ te,
    const bf16* __restrict__ WI, const float* __restrict__ gb, float* __restrict__ out)
{
    __shared__ __align__(16) char sm[81920];
    bf16* TE2 = (bf16*)(sm + OFF_TE2);
    bf16* XT  = (bf16*)(sm + OFF_XT);
    bf16* PN  = (bf16*)(sm + OFF_PN);
    bf16* WT  = (bf16*)(sm + OFF_WT);
    bf16* VT  = (bf16*)(sm + OFF_WT);
    bf16* OWT = (bf16*)(sm + OFF_WT);
    bf16* W1S = (bf16*)(sm + OFF_PN);
    bf16* W1X = (bf16*)(sm + OFF_XT) + 4608;   // dbuf in dead XT region (rows 64..95)
    bf16* P   = (bf16*)(sm + OFF_PN + 4608);
    bf16* CWs = (bf16*)(sm + OFF_PN);
    bf16* W2T = (bf16*)(sm + OFF_W2T);
    bf16* CON = (bf16*)(sm + OFF_CON);
    bf16* OT  = (bf16*)(sm + OFF_TE2);

    int tid = threadIdx.x;
    int w = tid >> 6, lane = tid & 63;
    int g = lane >> 4, c = lane & 15;
    int t0g = blockIdx.x * 128;               // global token base
    int b = t0g >> 14, n0 = t0g & (NTOK-1);
    const ffrag fz = {0.f,0.f,0.f,0.f};

    // ---------- phase 0: direct fp32 load + in-LDS transpose (x -> XT, te -> TE2) ----------
    {
        bf16* Tx = PN;    // temp [64][136] channel-major (PN region, dead now)
        bf16* Tt = WT;    // temp [64][136] channel-major (WT region, staged later)
        if (tid < 16) ((uint4*)CON)[tid] = ((const uint4*)(WI + WI_CONST))[tid];  // ln1w|ln1b
        int c0 = tid >> 3, j16 = (tid & 7) * 16;
        const float* xp = x  + (size_t)b*64*NTOK + (size_t)c0*NTOK + n0 + j16;
        const float* tp = te + (size_t)b*64*NTOK + (size_t)c0*NTOK + n0 + j16;
        float4 a0 = *(const float4*)(xp);
        float4 a1 = *(const float4*)(xp + 4);
        float4 a2 = *(const float4*)(xp + 8);
        float4 a3 = *(const float4*)(xp + 12);
        float4 e0 = *(const float4*)(tp);
        float4 e1 = *(const float4*)(tp + 4);
        float4 e2 = *(const float4*)(tp + 8);
        float4 e3 = *(const float4*)(tp + 12);
        uint4 o0, o1;
        o0.x = cvtpk(a0.x, a0.y); o0.y = cvtpk(a0.z, a0.w);
        o0.z = cvtpk(a1.x, a1.y); o0.w = cvtpk(a1.z, a1.w);
        o1.x = cvtpk(a2.x, a2.y); o1.y = cvtpk(a2.z, a2.w);
        o1.z = cvtpk(a3.x, a3.y); o1.w = cvtpk(a3.z, a3.w);
        *(uint4*)(Tx + c0*136 + j16)     = o0;
        *(uint4*)(Tx + c0*136 + j16 + 8) = o1;
        o0.x = cvtpk(e0.x, e0.y); o0.y = cvtpk(e0.z, e0.w);
        o0.z = cvtpk(e1.x, e1.y); o0.w = cvtpk(e1.z, e1.w);
        o1.x = cvtpk(e2.x, e2.y); o1.y = cvtpk(e2.z, e2.w);
        o1.z = cvtpk(e3.x, e3.y); o1.w = cvtpk(e3.z, e3.w);
        *(uint4*)(Tt + c0*136 + j16)     = o0;
        *(uint4*)(Tt + c0*136 + j16 + 8) = o1;
        __syncthreads();
        #pragma unroll
        for (int p = 0; p < 2; ++p){
            int idx = p*512 + tid;
            int tok = idx & 127, seg = idx >> 7;      // seg constant per wave -> 2-way banks
            const bf16* rx = Tx + seg*1088 + tok;
            const bf16* rt = Tt + seg*1088 + tok;
            uint4 ox, ot;
            ox.x = (unsigned)bu(rx[0])   | ((unsigned)bu(rx[136]) << 16);
            ox.y = (unsigned)bu(rx[272]) | ((unsigned)bu(rx[408]) << 16);
            ox.z = (unsigned)bu(rx[544]) | ((unsigned)bu(rx[680]) << 16);
            ox.w = (unsigned)bu(rx[816]) | ((unsigned)bu(rx[952]) << 16);
            *(uint4*)(XT + tok*72 + seg*8) = ox;
            ot.x = (unsigned)bu(rt[0])   | ((unsigned)bu(rt[136]) << 16);
            ot.y = (unsigned)bu(rt[272]) | ((unsigned)bu(rt[408]) << 16);
            ot.z = (unsigned)bu(rt[544]) | ((unsigned)bu(rt[680]) << 16);
            ot.w = (unsigned)bu(rt[952-136]) | ((unsigned)bu(rt[952]) << 16);
            *(uint4*)(TE2 + tok*64 + seg*8) = ot;
        }
    }
    __syncthreads();
    // ---------- phase 1: LN1 (TE2 -> PN, over dead Tx) + stage qkv weights (over dead Tt) ----------
    {
        ln_phase(TE2, PN, CON, CON + 64, tid);
        const uint4* wq = (const uint4*)(WI + WI_QKV);   // 1728 uint4 = 3x[64][72]
        for (int i = tid; i < 1728; i += 512) ((uint4*)WT)[i] = wq[i];
    }
    __syncthreads();
    // ---------- phase 2: QKV MFMA (8 waves x 16-row strips) ----------
    {
        if (tid < 24) ((uint4*)CON)[tid] = ((const uint4*)(WI + WI_CONST + 128))[tid]; // qb|kb|vb
        ffrag accQ[4], accK[4], accV[4];
        #pragma unroll
        for (int nt=0;nt<4;++nt){ accQ[nt]=fz; accK[nt]=fz; accV[nt]=fz; }
        bfrag aQ[2], aX[2];
        #pragma unroll
        for (int k2=0;k2<2;++k2){
            aQ[k2] = ld_frag(PN + (w*16)*72 + k2*32, 72);
            aX[k2] = ld_frag(XT + (w*16)*72 + k2*32, 72);
        }
        __builtin_amdgcn_s_setprio(1);
        for (int nt = 0; nt < 4; ++nt){
            #pragma unroll
            for (int k2 = 0; k2 < 2; ++k2){
                bfrag bq2 = ld_frag(WT +        nt*16*72 + k2*32, 72);
                bfrag bk2 = ld_frag(WT + 4608 + nt*16*72 + k2*32, 72);
                bfrag bv2 = ld_frag(WT + 9216 + nt*16*72 + k2*32, 72);
                accQ[nt] = MFMA(aQ[k2], bq2, accQ[nt]);
                accK[nt] = MFMA(aX[k2], bk2, accK[nt]);
                accV[nt] = MFMA(aX[k2], bv2, accV[nt]);
            }
        }
        __builtin_amdgcn_s_setprio(0);
        __syncthreads();   // all PN/XT/WT reads done; regions become Q / K / VT
        int rq = g*4;
        #pragma unroll
        for (int nt=0;nt<4;++nt){
            int n = nt*16 + c;
            float bq3 = b2f(CON[n]), bk3 = b2f(CON[64+n]), bv3 = b2f(CON[128+n]);
            #pragma unroll
            for (int r=0;r<4;++r){
                int m = w*16 + rq + r;
                stb(PN + m*72 + n, (accQ[nt][r] + bq3) * SCALE_Q);    // Q (pre-scaled)
                stb(XT + m*72 + n, accK[nt][r] + bk3);                // K
                // V -> VT transposed, half-tile key perm:
                // col kp = (m>>6)*64 + (m&15)*4 + ((m>>4)&3)
                int kp = ((m >> 6) << 6) + (m & 15)*4 + ((m >> 4) & 3);
                stb(VT + (5*(n>>2) + (n&3))*136 + kp, accV[nt][r] + bv3);
            }
        }
        // ones rows (row 5h+4) for the l-trick — one uint4 per thread
        if (tid < 256){
            int row = 5*(tid >> 4) + 4, col8 = (tid & 15)*8;
            uint4 ov; ov.x = ov.y = ov.z = ov.w = 0x3f803f80u;
            *(uint4*)(VT + row*136 + col8) = ov;
        }
    }
    __syncthreads();
    // ---------- phase 3: attention (block-diag, 16 heads, hd=4; 2 heads/wave, K-halved) ----------
    {
        bfrag bq[8];
        #pragma unroll
        for (int nt = 0; nt < 8; ++nt) bq[nt] = ld_frag(XT + nt*16*72 + (w>>2)*32, 72);
        __syncthreads();                       // K region becomes P scratch
        bf16* Pw = XT + w*1024;                // per-wave [16][64]
        #pragma unroll 1
        for (int hh = 0; hh < 2; ++hh){
            int h = w*2 + hh;
            int ag = w & 3;                    // active quad for A build
            bfrag bv4[4];                      // [kh*2 + ks]
            #pragma unroll
            for (int kk = 0; kk < 4; ++kk)
                bv4[kk] = ld_frag(VT + (5*h)*136 + (kk>>1)*64 + (kk&1)*32, 136);
            #pragma unroll 2
            for (int qt = 0; qt < 8; ++qt){
                int q = qt*16 + c;
                uint2 qv = *(const uint2*)(PN + q*72 + h*4);
                union { bfrag f; uint2 u[2]; } A;
                uint2 z2; z2.x = 0u; z2.y = 0u;
                uint2 sel = (g == ag) ? qv : z2;
                if (hh){ A.u[0] = z2;  A.u[1] = sel; }
                else   { A.u[0] = sel; A.u[1] = z2;  }
                ffrag og = fz;
                #pragma unroll
                for (int kh = 0; kh < 2; ++kh){
                    ffrag acc[4];
                    __builtin_amdgcn_s_setprio(1);
                    #pragma unroll
                    for (int nt = 0; nt < 4; ++nt) acc[nt] = MFMA(A.f, bq[kh*4+nt], fz);
                    __builtin_amdgcn_s_setprio(0);
                    #pragma unroll
                    for (int nt = 0; nt < 4; ++nt){
                        #pragma unroll
                        for (int r = 0; r < 4; ++r) acc[nt][r] = exp2f(acc[nt][r]);
                    }
                    // pack half-tile P [16][64]: row 4g+r, logical octet c>>1 (XOR row&7),
                    // within-octet (c&1)*4 + nt  (key perm kp'' = (m&15)*4 + (m>>4))
                    #pragma unroll
                    for (int r = 0; r < 4; ++r){
                        uint2 pk;
                        pk.x = cvtpk(acc[0][r], acc[1][r]);
                        pk.y = cvtpk(acc[2][r], acc[3][r]);
                        int row = 4*g + r;
                        *(uint2*)(Pw + row*64 + (((c>>1) ^ (row&7)) << 3) + ((c&1) << 2)) = pk;
                    }
                    // PV partial over this K-half (ones col 4 accumulates l)
                    __builtin_amdgcn_s_setprio(1);
                    #pragma unroll
                    for (int ks = 0; ks < 2; ++ks){
                        bfrag ap = *(const bfrag*)(Pw + c*64 + (((ks*4 + g) ^ (c&7)) << 3));
                        og = MFMA(ap, bv4[kh*2 + ks], og);
                    }
                    __builtin_amdgcn_s_setprio(0);
                }
                // broadcast l from lanes c==4, normalize, write O over Q (own head's cols)
                #pragma unroll
                for (int r = 0; r < 4; ++r){
                    float lr = __shfl(og[r], (lane & 48) | 4, 64);
                    if (c < 4)
                        stb(PN + (qt*16 + 4*g + r)*72 + h*4 + c, og[r] * fastrcp(lr));
                }
            }
        }
    }
    __syncthreads();
    // ---------- phase 3.5: o-proj (O @ ow^T + ob) + residual te, fused -> h in TE2 ----------
    {
        const uint4* oi = (const uint4*)(WI + WI_OW);
        for (int i = tid; i < 576; i += 512) ((uint4*)OWT)[i] = oi[i];
        if (tid < 24) ((uint4*)CON)[tid] = ((const uint4*)(WI + WI_CONST + 320))[tid]; // ob|ln2w|ln2b
        __syncthreads();
        ffrag acc2[4];
        #pragma unroll
        for (int nt=0;nt<4;++nt) acc2[nt] = fz;
        bfrag af2[2];
        #pragma unroll
        for (int k2=0;k2<2;++k2)
            af2[k2] = ld_frag(PN + (w*16)*72 + k2*32, 72);
        __builtin_amdgcn_s_setprio(1);
        #pragma unroll
        for (int nt=0;nt<4;++nt){
            #pragma unroll
            for (int k2=0;k2<2;++k2){
                bfrag bf_ = ld_frag(OWT + nt*16*72 + k2*32, 72);
                acc2[nt] = MFMA(af2[k2], bf_, acc2[nt]);
            }
        }
        __builtin_amdgcn_s_setprio(0);
        // epilogue: h = o-proj + ob + te, written in place over te (each (m,n) single-owner)
        int rq = g*4;
        #pragma unroll
        for (int nt=0;nt<4;++nt){
            int n = nt*16 + c;
            float bo = b2f(CON[n]);
            #pragma unroll
            for (int r=0;r<4;++r){
                int m = w*16 + rq + r;
                stb(TE2 + m*64 + n, acc2[nt][r] + bo + b2f(TE2[m*64 + n]));
            }
        }
    }
    __syncthreads();
    // ---------- phase 5: LN2 (TE2 -> HN in XT) with W2T staging split around it ----------
    {
        const uint4* w2i = (const uint4*)(WI + WI_W2);
        uint4 w2r0 = w2i[tid];               // issue early: HBM latency hides under LN2
        uint4 w2r1 = w2i[512 + tid];
        uint4 w2r2 = w2i[1024 + tid];
        uint4 w2r3 = w2i[1536 + tid];
        ln_phase(TE2, XT, CON + 64, CON + 128, tid);
        ((uint4*)W2T)[tid]        = w2r0;    // write late (W2T region dead since 3.5)
        ((uint4*)W2T)[512 + tid]  = w2r1;
        ((uint4*)W2T)[1024 + tid] = w2r2;
        ((uint4*)W2T)[1536 + tid] = w2r3;
    }
    __syncthreads();
    // ---------- phase 6: FFN (fc1+GELU+fc2, K-grouped, dbuf W1) + residual ----------
    {
        if (tid < 48) ((uint4*)CON)[tid] = ((const uint4*)(WI + WI_CONST + 512))[tid]; // b1|b2|cb
        bfrag af[2];
        #pragma unroll
        for (int k2=0;k2<2;++k2)
            af[k2] = ld_frag(XT + (w*16)*72 + k2*32, 72);
        ffrag acc2[4];
        #pragma unroll
        for (int nt=0;nt<4;++nt) acc2[nt] = fz;
        int rq = g*4;
        // register prefetch of W1 chunks (288 uint4 each); double-buffered LDS (W1S / W1X)
        const uint4* w1i = (const uint4*)(WI + WI_W1);
        uint4 pA;
        if (tid < 288) pA = w1i[tid];
        for (int gg = 0; gg < 8; ++gg){
            bf16* Wb = (gg & 1) ? W1X : W1S;
            if (tid < 288){
                ((uint4*)Wb)[tid] = pA;
                if (gg < 7) pA = w1i[(gg+1)*288 + tid];
            }
            __syncthreads();       // single barrier per iteration (dbuf makes 2nd unnecessary)
            ffrag accg[2];
            #pragma unroll
            for (int ntl=0;ntl<2;++ntl) accg[ntl] = fz;
            __builtin_amdgcn_s_setprio(1);
            #pragma unroll
            for (int ntl=0;ntl<2;++ntl){
                #pragma unroll
                for (int k2=0;k2<2;++k2){
                    bfrag bf_ = ld_frag(Wb + ntl*16*72 + k2*32, 72);
                    accg[ntl] = MFMA(af[k2], bf_, accg[ntl]);
                }
            }
            __builtin_amdgcn_s_setprio(0);
            // GELU -> P (own rows; no barrier needed before own-row frag reads)
            // octet XOR-swizzle (octet ^= (row>>1)&3) -> fc2 A-frag reads bank-even
            #pragma unroll
            for (int ntl=0;ntl<2;++ntl){
                int n = ntl*16 + c;
                float bb = b2f(CON[gg*32 + n]);
                #pragma unroll
                for (int r=0;r<4;++r){
                    int m = w*16 + rq + r;
                    float xv = accg[ntl][r] + bb;
                    stb(P + m*32 + ((((n>>3) ^ ((m>>1)&3)) << 3) | (n & 7)), gelu_t(xv));
                }
            }
            // fc2 partial (K-chunk gg), swizzled P + swizzled W2T frags
            {
                int rr = w*16 + c;
                bfrag ap = *(const bfrag*)(P + rr*32 + ((g ^ ((rr>>1)&3)) << 3));
                __builtin_amdgcn_s_setprio(1);
                #pragma unroll
                for (int nt=0;nt<4;++nt){
                    int n = nt*16 + c;
                    int chunk = gg*4 + g;
                    bfrag bf2 = *(const bfrag*)(W2T + n*256 + ((chunk ^ (n&7)) << 3));
                    acc2[nt] = MFMA(ap, bf2, acc2[nt]);
                }
                __builtin_amdgcn_s_setprio(0);
            }
        }
        // prefetch conv weights to regs (write after barrier; CWs region dead post-B9)
        const uint4* ci = (const uint4*)(WI + WI_CW);
        uint4 cw0 = ci[tid];
        uint4 cw1 = cw0;
        if (tid < 64) cw1 = ci[512 + tid];
        __syncthreads();   // B9: all Wb/P/W2T reads done; XT & CWs regions free
        // h2 = fc2 + b2 + h  -> h2 in XT (af already in regs for all waves)
        #pragma unroll
        for (int nt=0;nt<4;++nt){
            int n = nt*16 + c;
            float bb = b2f(CON[256+n]);
            #pragma unroll
            for (int r=0;r<4;++r){
                int m = w*16 + rq + r;
                stb(XT + m*72 + n, acc2[nt][r] + bb + b2f(TE2[m*64 + n]));
            }
        }
        // conv-weight staging from regs (same barrier window as h2 writes)
        ((uint4*)CWs)[tid] = cw0;
        if (tid < 64) ((uint4*)CWs)[512 + tid] = cw1;
    }
    __syncthreads();
    // ---------- phase 7: 1x1 conv -> OT [64][128] (over h-in-TE2 region; reads XT) ----------
    {
        bfrag ac[2];
        #pragma unroll
        for (int k2=0;k2<2;++k2) ac[k2] = ld_frag(CWs + ((w&3)*16)*72 + k2*32, 72);
        int rq = g*4;
        #pragma unroll
        for (int nt4 = 0; nt4 < 4; ++nt4){
            int nt = (w>>2)*4 + nt4;
            ffrag accc = fz;
            __builtin_amdgcn_s_setprio(1);
            #pragma unroll
            for (int k2=0;k2<2;++k2){
                bfrag bh = ld_frag(XT + nt*16*72 + k2*32, 72);
                accc = MFMA(ac[k2], bh, accc);
            }
            __builtin_amdgcn_s_setprio(0);
            int tok = nt*16 + c;
            #pragma unroll
            for (int r=0;r<4;++r){
                int co = (w&3)*16 + rq + r;
                stb(OT + co*128 + tok, accc[r] + b2f(CON[320+co]));
            }
        }
    }
    __syncthreads();
    // ---------- phase 8: out = (1+gamma)*(conv + x) + beta ----------
    {
        int cc = tid >> 3, seg = (tid & 7)*16;
        float gamma = 1.f + gb[b*128 + cc];
        float beta  = gb[b*128 + 64 + cc];
        const size_t gbase = (size_t)b*64*NTOK + (size_t)cc*NTOK + n0 + seg;
        #pragma unroll
        for (int u = 0; u < 4; ++u){
            float cv[4];
            ld4(OT + cc*128 + seg + u*4, cv);
            float4 xv = *(const float4*)(x + gbase + u*4);
            float4 ov;
            ov.x = fmaf(gamma, cv[0]+xv.x, beta);
            ov.y = fmaf(gamma, cv[1]+xv.y, beta);
            ov.z = fmaf(gamma, cv[2]+xv.z, beta);
            ov.w = fmaf(gamma, cv[3]+xv.w, beta);
            *(float4*)(out + gbase + u*4) = ov;
        }
    }
}

extern "C" void kernel_launch(void* const* d_in, const int* in_sizes, int n_in,
                              void* d_out, int out_size, void* d_ws, size_t ws_size,
                              hipStream_t stream){
    const float* x   = (const float*)d_in[0];
    const float* te  = (const float*)d_in[1];
    const float* qw  = (const float*)d_in[2];
    const float* qb  = (const float*)d_in[3];
    const float* kw  = (const float*)d_in[4];
    const float* kb  = (const float*)d_in[5];
    const float* vw  = (const float*)d_in[6];
    const float* vb  = (const float*)d_in[7];
    const float* ow  = (const float*)d_in[8];
    const float* ob  = (const float*)d_in[9];
    const float* ln1w= (const float*)d_in[10];
    const float* ln1b= (const float*)d_in[11];
    const float* ln2w= (const float*)d_in[12];
    const float* ln2b= (const float*)d_in[13];
    const float* w1  = (const float*)d_in[14];
    const float* b1  = (const float*)d_in[15];
    const float* w2  = (const float*)d_in[16];
    const float* b2  = (const float*)d_in[17];
    const float* cw  = (const float*)d_in[18];
    const float* cb  = (const float*)d_in[19];
    const float* m1w = (const float*)d_in[20];
    const float* m1b = (const float*)d_in[21];
    const float* m2w = (const float*)d_in[22];
    const float* m2b = (const float*)d_in[23];

    char* ws = (char*)d_ws;
    float* pool = (float*)(ws);                   // 32768 B
    float* gbp  = (float*)(ws + 32768);           // 4096 B
    bf16* WI    = (bf16*)(ws + 36864);            // 117504 B weight/const images

    wprep_kernel<<<(WI_TOT + 255)/256, 256, 0, stream>>>(
        qw, kw, vw, ow, cw, w1, w2,
        ln1w, ln1b, qb, kb, vb, ob, ln2w, ln2b, b1, b2, cb, WI);
    pool_kernel<<<NB*64, 256, 0, stream>>>(te, pool);
    film_kernel<<<NB, 128, 0, stream>>>(pool, m1w, m1b, m2w, m2b, gbp);
    mega_kernel<<<TOTTOK/128, 512, 0, stream>>>(x, te, WI, gbp, (float*)d_out);
}